// Round 21
// baseline (974.290 us; speedup 1.0000x reference)
//
#include <hip/hip_runtime.h>
#include <stdint.h>

#define B_    8
#define CCH   64
#define HW_   4096
#define C512  512
#define XSTR8 5288   // shorts per xl kgrp (660*8=5280 + 8 pad -> 10,576 B % 128 = 80, staggered)
#define WSTR  520    // shorts per wl (tap,lkg) sub-block (512 + 8 pad -> 1040 B % 128 = 16)

typedef __attribute__((ext_vector_type(8))) short short8v;
typedef __attribute__((ext_vector_type(4))) float f32x4;
typedef __attribute__((ext_vector_type(4))) unsigned short ushort4v;

__device__ __constant__ int PERM[8][8] = {
  {0,1,2,3,4,5,6,7},
  {3,0,1,2,5,6,7,4},
  {2,3,0,1,6,7,4,5},
  {1,2,3,0,7,4,5,6},
  {4,5,6,7,0,1,2,3},
  {5,6,7,4,3,0,1,2},
  {6,7,4,5,2,3,0,1},
  {7,4,5,6,1,2,3,0},
};

__device__ inline float bf2f(unsigned int u){
  union { unsigned int i; float f; } v; v.i = u << 16; return v.f;
}
__device__ inline unsigned short f2bf(float f){
  union { float f; unsigned int i; } v; v.f = f;
  return (unsigned short)((v.i + 0x7FFFu + ((v.i >> 16) & 1u)) >> 16);
}
// round-half-up pairwise pack (cheap; |err| <= 1ulp, fine vs 0.109 threshold)
__device__ inline unsigned int scale2(unsigned int packed, float a0, float a1, float f){
  float v0 = bf2f(packed & 0xffffu) * a0 * f;
  float v1 = bf2f(packed >> 16)     * a1 * f;
  unsigned int i0 = __float_as_uint(v0), i1 = __float_as_uint(v1);
  return ((i0 + 0x8000u) >> 16) | ((i1 + 0x8000u) & 0xffff0000u);
}
__device__ inline float sigmoidf_(float x){ return 1.f / (1.f + __expf(-x)); }

__device__ __forceinline__ void gload_lds16(const unsigned short* g, unsigned short* l){
  __builtin_amdgcn_global_load_lds(
      (const __attribute__((address_space(1))) unsigned int*)(g),
      (__attribute__((address_space(3))) unsigned int*)(l), 16, 0, 0);
}

// ---------------- BN + ReLU + transpose body + fused channel AND spatial stats -----------
template<int BF>
__device__ __forceinline__ void bnrelu_body(
    const float* __restrict__ xf, const unsigned short* __restrict__ xb,
    const float* __restrict__ gamma, const float* __restrict__ beta,
    const float* __restrict__ mean,  const float* __restrict__ var,
    unsigned short* __restrict__ yT,
    float* __restrict__ csum, unsigned int* __restrict__ cmax,
    float* __restrict__ f2, int bid){
  __shared__ float lds[64 * 66];
  int b  = bid >> 9;
  int r  = bid & 511;
  int ct = r >> 6, pt = r & 63;
  int c0 = ct * 64, p0 = pt * 64;
  int t  = threadIdx.x;
  int cc = t >> 2, q = t & 3;
  int c512 = c0 + cc;
  int ch = c512 >> 3;
  float inv = gamma[ch] * rsqrtf(var[ch] + 2e-5f);
  float sh  = beta[ch] - mean[ch] * inv;
  float s_ = 0.f, m_ = 0.f;
#pragma unroll
  for (int i = 0; i < 4; ++i){
    float r0, r1, r2, r3;
    if (BF){
      const unsigned short* src = xb + ((size_t)(b * C512 + c512)) * HW_ + p0;
      ushort4v u = *(const ushort4v*)(src + i * 16 + q * 4);
      r0 = bf2f(u[0]); r1 = bf2f(u[1]); r2 = bf2f(u[2]); r3 = bf2f(u[3]);
    } else {
      const float* src = xf + ((size_t)(b * C512 + c512)) * HW_ + p0;
      float4 v = *(const float4*)(src + i * 16 + q * 4);
      r0 = v.x; r1 = v.y; r2 = v.z; r3 = v.w;
    }
    float a0 = fmaxf(r0 * inv + sh, 0.f);
    float a1 = fmaxf(r1 * inv + sh, 0.f);
    float a2 = fmaxf(r2 * inv + sh, 0.f);
    float a3 = fmaxf(r3 * inv + sh, 0.f);
    int pp = i * 16 + q * 4;
    lds[(pp + 0) * 66 + cc] = a0;
    lds[(pp + 1) * 66 + cc] = a1;
    lds[(pp + 2) * 66 + cc] = a2;
    lds[(pp + 3) * 66 + cc] = a3;
    s_ += (a0 + a1) + (a2 + a3);
    m_ = fmaxf(m_, fmaxf(fmaxf(a0, a1), fmaxf(a2, a3)));
  }
  s_ += __shfl_down(s_, 2); s_ += __shfl_down(s_, 1);
  m_ = fmaxf(m_, __shfl_down(m_, 2)); m_ = fmaxf(m_, __shfl_down(m_, 1));
  if (q == 0){
    atomicAdd(&csum[b * C512 + c512], s_);
    atomicMax(&cmax[b * C512 + c512], __float_as_uint(m_));
  }
  __syncthreads();
  // transposed bf16 store
  int cc4 = (t & 15) * 4, g0 = t >> 4;
  unsigned short* dst = yT + ((size_t)(b * HW_ + p0)) * C512 + c0 + cc4;
#pragma unroll
  for (int i = 0; i < 4; ++i){
    int pp = i * 16 + g0;
    float2 v0 = *(const float2*)&lds[pp * 66 + cc4];
    float2 v1 = *(const float2*)&lds[pp * 66 + cc4 + 2];
    ushort4v o;
    o[0] = f2bf(v0.x); o[1] = f2bf(v0.y); o[2] = f2bf(v1.x); o[3] = f2bf(v1.y);
    *(ushort4v*)(dst + (size_t)pp * C512) = o;
  }
  // fused spatial stats: reduce this block's 8 ci per (s, px), merge via atomics.
#pragma unroll
  for (int k = 0; k < 2; ++k){
    int task = t + k * 256;
    int px = task >> 3, s = task & 7;
    const float* row = &lds[px * 66 + s];
    float sm = row[0], mx = row[0];
#pragma unroll
    for (int j = 1; j < 8; ++j){ float v = row[j * 8]; sm += v; mx = fmaxf(mx, v); }
    atomicAdd(&f2[((size_t)(b * 2 + 0) * 8 + s) * 4096 + p0 + px], sm);
    atomicMax((unsigned int*)&f2[((size_t)(b * 2 + 1) * 8 + s) * 4096 + p0 + px],
              __float_as_uint(mx));
  }
}

template<int BF>
__global__ void k_bnrelu_tr(const float* __restrict__ xf, const unsigned short* __restrict__ xb,
                            const float* __restrict__ gamma, const float* __restrict__ beta,
                            const float* __restrict__ mean,  const float* __restrict__ var,
                            unsigned short* __restrict__ yT,
                            float* __restrict__ csum, unsigned int* __restrict__ cmax,
                            float* __restrict__ f2){
  bnrelu_body<BF>(xf, xb, gamma, beta, mean, var, yT, csum, cmax, f2, blockIdx.x);
}

// ---------------- conv-weight transform body -> wt[g][kc16][tap9][kl4][co64][8] bf16 ------
__device__ __forceinline__ void cw_body(const float* __restrict__ w,
                                        unsigned short* __restrict__ wt, int e){
  int j  = e & 7;
  int co = (e >> 3) & 63;
  int kl = (e >> 9) & 3;
  int r  = e >> 11;          // ((g*16 + kc)*9 + tap)
  int tap = r % 9; int r2 = r / 9;
  int kc = r2 & 15; int g = r2 >> 4;
  int c512 = kc * 32 + kl * 8 + j;
  int ci = c512 >> 3, s = c512 & 7;
  int ty = tap / 3, tx = tap % 3;
  int a = g >> 2, bb = g & 3;
  int sy, sx;
  if      (bb == 0){ sy = ty;     sx = tx;     }
  else if (bb == 1){ sy = tx;     sx = 2 - ty; }
  else if (bb == 2){ sy = 2 - ty; sx = 2 - tx; }
  else             { sy = 2 - tx; sx = ty;     }
  if (a) sx = 2 - sx;
  int ps = PERM[g][s];
  wt[e] = f2bf(w[((size_t)(co * 64 + ci) * 8 + ps) * 9 + sy * 3 + sx]);
}

// K7 (layer 0): weight transform + zero stat buffers (64 KB) + zero f2 (2 MB)
__global__ void k_cw(const float* __restrict__ w, unsigned short* __restrict__ wt,
                     unsigned int* __restrict__ zbuf, float* __restrict__ f2){
  int e = blockIdx.x * 256 + threadIdx.x;
  if (e < 16384) zbuf[e] = 0u;
  if (e < 524288) f2[e] = 0.f;
  if (e >= 8 * 16 * 9 * 4 * 64 * 8) return;
  cw_body(w, wt, e);
}

// Merged (layer 1): blocks 0..9215 = cw(L1); blocks 9216..13311 = bnrelu<bf16>(L1).
__global__ void k_cwbn(const float* __restrict__ w, unsigned short* __restrict__ wt,
                       const unsigned short* __restrict__ h1b,
                       const float* __restrict__ gamma, const float* __restrict__ beta,
                       const float* __restrict__ mean,  const float* __restrict__ var,
                       unsigned short* __restrict__ yT,
                       float* __restrict__ csum, unsigned int* __restrict__ cmax,
                       float* __restrict__ f2){
  int bid = blockIdx.x;
  if (bid < 9216){
    int e = bid * 256 + threadIdx.x;
    if (e < 8 * 16 * 9 * 4 * 64 * 8) cw_body(w, wt, e);
    return;
  }
  bnrelu_body<1>(nullptr, h1b, gamma, beta, mean, var, yT, csum, cmax, f2, bid - 9216);
}

// ---------------- K_att: blocks 0..63 = channel-MLP -> ac ; blocks 64..319 = sconv -> sp --
__global__ void k_att(const float* __restrict__ f2, const float* __restrict__ saw,
                      float* __restrict__ sp,
                      const float* __restrict__ csum, const unsigned int* __restrict__ cmax,
                      const float* __restrict__ w1, const float* __restrict__ w2,
                      float* __restrict__ ac){
  __shared__ __align__(16) float shm[16260];   // 65,040 B, aliased by both halves
  int bid = blockIdx.x;
  int t = threadIdx.x;
  if (bid < 64){
    float* vA = shm;            // 512
    float* vM = shm + 512;      // 512
    float* wred = shm + 1024;   // 16
    float* rr = shm + 1040;     // 2
    int b = bid >> 3, g = bid & 7;
    for (int j = t; j < 512; j += 256){
      int c = j >> 3, h = j & 7;
      int srcj = (c << 3) + PERM[g][h];
      vA[j] = csum[b * 512 + srcj] * (1.f / 4096.f);
      vM[j] = __uint_as_float(cmax[b * 512 + srcj]);
    }
    __syncthreads();
    float pa0 = 0, pa1 = 0, pm0 = 0, pm1 = 0;
    for (int j = t; j < 512; j += 256){
      float wa = w1[j], wb = w1[512 + j];
      pa0 += vA[j] * wa; pa1 += vA[j] * wb;
      pm0 += vM[j] * wa; pm1 += vM[j] * wb;
    }
#pragma unroll
    for (int off = 32; off >= 1; off >>= 1){
      pa0 += __shfl_down(pa0, off); pa1 += __shfl_down(pa1, off);
      pm0 += __shfl_down(pm0, off); pm1 += __shfl_down(pm1, off);
    }
    int wv = t >> 6, ln = t & 63;
    if (ln == 0){ wred[wv*4+0] = pa0; wred[wv*4+1] = pa1; wred[wv*4+2] = pm0; wred[wv*4+3] = pm1; }
    __syncthreads();
    if (t == 0){
      float hA0 = wred[0] + wred[4] + wred[8]  + wred[12];
      float hA1 = wred[1] + wred[5] + wred[9]  + wred[13];
      float hM0 = wred[2] + wred[6] + wred[10] + wred[14];
      float hM1 = wred[3] + wred[7] + wred[11] + wred[15];
      rr[0] = fmaxf(hA0, 0.f) + fmaxf(hM0, 0.f);
      rr[1] = fmaxf(hA1, 0.f) + fmaxf(hM1, 0.f);
    }
    __syncthreads();
    float r0 = rr[0], r1 = rr[1];
    for (int j = t; j < 512; j += 256){
      float z = r0 * w2[j * 2] + r1 * w2[j * 2 + 1];
      ac[(size_t)(b * 8 + g) * 512 + j] = sigmoidf_(z);
    }
    return;
  }
  float* slab = shm;            // 8960
  float* wspl = shm + 8960;     // 6272
  float* part = shm + 15232;    // 1024
  int sb = bid - 64;
  int b = sb >> 5, strip = sb & 31;
  int R0 = strip * 2;
  for (int i = t; i < 6272; i += 256){
    int g = i & 7; int r = i >> 3;
    int kx = r % 7; int r2 = r / 7;
    int ky = r2 % 7; int tc = r2 / 7;
    int m = tc >> 3, s = tc & 7;
    int a = g >> 2, bb = g & 3;
    int sy, sx;
    if      (bb == 0){ sy = ky;     sx = kx;     }
    else if (bb == 1){ sy = kx;     sx = 6 - ky; }
    else if (bb == 2){ sy = 6 - ky; sx = 6 - kx; }
    else             { sy = 6 - kx; sx = ky;     }
    if (a) sx = 6 - sx;
    int ps = PERM[g][s];
    float wv_ = saw[((m * 8 + ps) * 7 + sy) * 7 + sx];
    wspl[i] = (m == 0) ? wv_ * 0.015625f : wv_;
  }
  for (int i = t; i < 8960; i += 256){
    int tc = i / 560; int rem = i - tc * 560;
    int rr = rem / 70; int cc = rem - rr * 70;
    int gr = R0 + rr - 3, gc = cc - 3;
    float v = 0.f;
    if ((unsigned)gr < 64u && (unsigned)gc < 64u)
      v = f2[((size_t)(b * 16 + tc)) * 4096 + gr * 64 + gc];
    slab[i] = v;
  }
  __syncthreads();
  int tcH = t >> 7, p = t & 127;
  int r = p >> 6, x = p & 63;
  float acc[8] = {0,0,0,0,0,0,0,0};
  for (int tc = tcH * 8; tc < tcH * 8 + 8; ++tc){
    const float* sl = &slab[tc * 560 + r * 70 + x];
    for (int ky = 0; ky < 7; ++ky){
#pragma unroll
      for (int kx = 0; kx < 7; ++kx){
        float v = sl[ky * 70 + kx];
        const float* w8 = &wspl[((tc * 7 + ky) * 7 + kx) * 8];
#pragma unroll
        for (int g = 0; g < 8; ++g) acc[g] += v * w8[g];
      }
    }
  }
  if (tcH == 1){
#pragma unroll
    for (int g = 0; g < 8; ++g) part[p * 8 + g] = acc[g];
  }
  __syncthreads();
  if (tcH == 0){
    int px = strip * 128 + p;
#pragma unroll
    for (int g = 0; g < 8; ++g){
      float z = acc[g] + part[p * 8 + g];
      sp[((size_t)(b * 8 + g)) * 4096 + px] = sigmoidf_(z);
    }
  }
}

// ---------------- K8: main group conv (implicit GEMM, 16x16x32 bf16 MFMA) -----------------
// FAT-TILE variant: 256 thr / 4 waves, tile = 8 rows (512 px) per (b,g); each wave owns
// 64co x 128px (acc[4][8] = 128 VGPR). Same W LDS serves 2x MFMA; barriers/DMA per MFMA
// halve; B-reads/MFMA drop 0.5 -> 0.375. Grid 512 = 2 blocks/CU, one clean round.
// LDS: xl 4*XSTR8*2 = 42,304 + wl 36*WSTR*2 = 37,440 + acs 2,048 = 81,792 <= 81,920.
template<int RES>
__global__ __launch_bounds__(256, 2)
void k_conv(const unsigned short* __restrict__ yT, const unsigned short* __restrict__ wt,
            const float* __restrict__ ac, const float* __restrict__ sp,
            const float* __restrict__ resid, float* __restrict__ outF,
            unsigned short* __restrict__ outB, float* __restrict__ f2z){
  __shared__ __align__(16) unsigned short xl[4 * XSTR8];
  __shared__ __align__(16) unsigned short wl[36 * WSTR];
  __shared__ float acs[512];
  int bid0 = blockIdx.x;
  int t = threadIdx.x;
  if (RES == 0){
    // re-zero f2 (524,288 floats) for layer-2's bnrelu atomics: 512 blocks x 256 thr x 4
    *(float4*)&f2z[(size_t)(bid0 * 256 + t) * 4] = make_float4(0.f, 0.f, 0.f, 0.f);
  }
  int bid = (bid0 & 7) * 64 + (bid0 >> 3);   // XCD swizzle (512 = 8*64, bijective)
  int b = bid >> 6, g = (bid >> 3) & 7, tile = bid & 7;
  int r0 = tile * 8;
  int wv = t >> 6, ln = t & 63;
  int lrow = ln & 15, lkg = ln >> 4;
  int cg = t & 3;

  const unsigned short* ybase = yT + ((size_t)b * HW_) * C512;
  const unsigned short* wbase = wt + ((size_t)g) * 16 * 9 * 2048;
  const float* spb = sp + ((size_t)(b * 8 + g)) * 4096;

  // ---- hoisted staging geometry: 2640 tasks = 660 hp x 4 cg ----
  unsigned int goff[11];
  float        fsc[11];
  int          xwb[11];
  uint4        xr[11];
#pragma unroll
  for (int it = 0; it < 11; ++it){
    int task = t + it * 256;
    bool act = (it < 10) || (t < 80);
    int hp = task >> 2;
    int hr = hp / 66, hc = hp - hr * 66;
    int gh = r0 + hr - 1, gw = hc - 1;
    bool inb = act && ((unsigned)gh < 64u) && ((unsigned)gw < 64u);
    goff[it] = inb ? (unsigned)((gh * 64 + gw) * C512 + cg * 8) : 0u;
    fsc[it]  = inb ? spb[gh * 64 + gw] : 0.f;
    xwb[it]  = cg * XSTR8 + hp * 8;
  }

  // ---- prologue: DMA W(0), prefetch X(0), fill acs ----
#pragma unroll
  for (int it = 0; it < 9; ++it){
    int task = t + it * 256;
    int sub = task >> 6, row = task & 63;
    gload_lds16(wbase + (size_t)task * 8, &wl[sub * WSTR + row * 8]);
  }
#pragma unroll
  for (int it = 0; it < 11; ++it)
    xr[it] = *(const uint4*)(ybase + goff[it]);
  for (int j = t; j < 512; j += 256) acs[j] = ac[(size_t)(b * 8 + g) * 512 + j];

  f32x4 acc[4][8];
#pragma unroll
  for (int mi = 0; mi < 4; ++mi)
#pragma unroll
    for (int ni = 0; ni < 8; ++ni)
      acc[mi][ni] = (f32x4){0.f, 0.f, 0.f, 0.f};
  __syncthreads();   // drains DMA(0) + X(0) loads; acs visible

  // ---- scale + write X(0) ----
  {
    float4 a8lo = *(const float4*)&acs[cg * 8];
    float4 a8hi = *(const float4*)&acs[cg * 8 + 4];
#pragma unroll
    for (int it = 0; it < 11; ++it){
      if (it < 10 || t < 80){
        float f = fsc[it];
        uint4 u = xr[it]; uint4 o;
        o.x = scale2(u.x, a8lo.x, a8lo.y, f);
        o.y = scale2(u.y, a8lo.z, a8lo.w, f);
        o.z = scale2(u.z, a8hi.x, a8hi.y, f);
        o.w = scale2(u.w, a8hi.z, a8hi.w, f);
        *(uint4*)&xl[xwb[it]] = o;
      }
    }
  }

  for (int kc = 0; kc < 16; ++kc){
    __syncthreads();   // xl(kc)/wl(kc) ready
    // ---- prefetch X(kc+1) (pinned before MFMA; drains under it) ----
    if (kc < 15){
#pragma unroll
      for (int it = 0; it < 11; ++it)
        xr[it] = *(const uint4*)(ybase + goff[it] + (kc + 1) * 32);
    }
    __builtin_amdgcn_sched_barrier(0);
    // ---- MFMA over LDS(kc): 4 m-frags x 8 n-frags per tap ----
    __builtin_amdgcn_s_setprio(1);
#pragma unroll
    for (int tap = 0; tap < 9; ++tap){
      const int ty = tap / 3, tx = tap % 3;
      short8v a[4], bv[8];
#pragma unroll
      for (int mi = 0; mi < 4; ++mi)
        a[mi] = *(const short8v*)&wl[(tap * 4 + lkg) * WSTR + (mi * 16 + lrow) * 8];
#pragma unroll
      for (int ni = 0; ni < 8; ++ni){
        int n = wv * 128 + ni * 16 + lrow;
        int hp = ((n >> 6) + ty) * 66 + (n & 63) + tx;
        bv[ni] = *(const short8v*)&xl[lkg * XSTR8 + hp * 8];
      }
#pragma unroll
      for (int mi = 0; mi < 4; ++mi)
#pragma unroll
        for (int ni = 0; ni < 8; ++ni)
          acc[mi][ni] = __builtin_amdgcn_mfma_f32_16x16x32_bf16(a[mi], bv[ni], acc[mi][ni], 0, 0, 0);
    }
    __builtin_amdgcn_s_setprio(0);
    __syncthreads();   // all reads of LDS(kc) done; X(kc+1) drained
    if (kc < 15){
      // ---- DMA W(kc+1) (in flight during X scale; drained at next top barrier) ----
      const unsigned short* wkc = wbase + (size_t)(kc + 1) * 9 * 2048;
#pragma unroll
      for (int it = 0; it < 9; ++it){
        int task = t + it * 256;
        int sub = task >> 6, row = task & 63;
        gload_lds16(wkc + (size_t)task * 8, &wl[sub * WSTR + row * 8]);
      }
      // ---- scale + write X(kc+1) ----
      int cb = (kc + 1) * 32;
      float4 a8lo = *(const float4*)&acs[cb + cg * 8];
      float4 a8hi = *(const float4*)&acs[cb + cg * 8 + 4];
#pragma unroll
      for (int it = 0; it < 11; ++it){
        if (it < 10 || t < 80){
          float f = fsc[it];
          uint4 u = xr[it]; uint4 o;
          o.x = scale2(u.x, a8lo.x, a8lo.y, f);
          o.y = scale2(u.y, a8lo.z, a8lo.w, f);
          o.z = scale2(u.z, a8hi.x, a8hi.y, f);
          o.w = scale2(u.w, a8hi.z, a8hi.w, f);
          *(uint4*)&xl[xwb[it]] = o;
        }
      }
    }
  }

  // ---- epilogue: C[co, pixel] -> [b][co][g][h][w]; RES? f32+resid : bf16 (h1) ----
#pragma unroll
  for (int mi = 0; mi < 4; ++mi){
#pragma unroll
    for (int ni = 0; ni < 8; ++ni){
      int n = wv * 128 + ni * 16 + lrow;
      int rr_ = n >> 6, ww = n & 63;
      int gh = r0 + rr_;
#pragma unroll
      for (int q = 0; q < 4; ++q){
        int co = mi * 16 + (ln >> 4) * 4 + q;
        size_t oidx = ((size_t)(b * 64 + co) * 8 + g) * 4096 + gh * 64 + ww;
        if (RES){
          outF[oidx] = acc[mi][ni][q] + resid[oidx];
        } else {
          outB[oidx] = f2bf(acc[mi][ni][q]);
        }
      }
    }
  }
}

// =========================================================================================
extern "C" void kernel_launch(void* const* d_in, const int* in_sizes, int n_in,
                              void* d_out, int out_size, void* d_ws, size_t ws_size,
                              hipStream_t stream){
  const size_t off_yT  = 0;                          // 33,554,432
  const size_t off_wt  = off_yT  + 33554432;         //  4,718,592
  const size_t off_f2  = off_wt  + 4718592;          //  2,097,152
  const size_t off_cs0 = off_f2  + 2097152;          //     16,384
  const size_t off_cm0 = off_cs0 + 16384;            //     16,384
  const size_t off_cs1 = off_cm0 + 16384;            //     16,384
  const size_t off_cm1 = off_cs1 + 16384;            //     16,384
  const size_t off_sp  = off_cm1 + 16384;            //  1,048,576
  const size_t off_ac  = off_sp  + 1048576;          //  1,048,576
  const size_t total   = off_ac  + 1048576;          // 42,532,864
  if (ws_size < total) return;

  char* ws = (char*)d_ws;
  unsigned short* yT  = (unsigned short*)(ws + off_yT);
  unsigned short* wtb = (unsigned short*)(ws + off_wt);
  float* f2    = (float*)(ws + off_f2);
  float* csum0 = (float*)(ws + off_cs0);
  unsigned int* cmax0 = (unsigned int*)(ws + off_cm0);
  float* csum1 = (float*)(ws + off_cs1);
  unsigned int* cmax1 = (unsigned int*)(ws + off_cm1);
  float* spb   = (float*)(ws + off_sp);
  float* acb   = (float*)(ws + off_ac);

  const float* x = (const float*)d_in[0];
  // h1 stored as bf16 in the UPPER half of d_out (33,554,432 B each half).
  unsigned short* h1b = (unsigned short*)((char*)d_out + 33554432);

  // ---- layer 0 ----
  // k_cw zeroes csum0..cmax1 (64 KB, contiguous after f2) + f2 (2 MB)
  k_cw<<<9216, 256, 0, stream>>>((const float*)d_in[5], wtb, (unsigned int*)csum0, f2);
  k_bnrelu_tr<0><<<4096, 256, 0, stream>>>(x, nullptr,
      (const float*)d_in[1], (const float*)d_in[2], (const float*)d_in[3], (const float*)d_in[4],
      yT, csum0, cmax0, f2);
  k_att<<<320, 256, 0, stream>>>(f2, (const float*)d_in[8], spb, csum0, cmax0,
      (const float*)d_in[6], (const float*)d_in[7], acb);
  k_conv<0><<<512, 256, 0, stream>>>(yT, wtb, acb, spb, nullptr, nullptr, h1b, f2);

  // ---- layer 1 (cw(L1) merged with bnrelu(L1); f2 re-zeroed by k_conv<0>) ----
  k_cwbn<<<13312, 256, 0, stream>>>((const float*)d_in[13], wtb, h1b,
      (const float*)d_in[9], (const float*)d_in[10], (const float*)d_in[11], (const float*)d_in[12],
      yT, csum1, cmax1, f2);
  k_att<<<320, 256, 0, stream>>>(f2, (const float*)d_in[16], spb, csum1, cmax1,
      (const float*)d_in[14], (const float*)d_in[15], acb);
  k_conv<1><<<512, 256, 0, stream>>>(yT, wtb, acb, spb, x, (float*)d_out, nullptr, nullptr);
}

// Round 22
// 399.983 us; speedup vs baseline: 2.4358x; 2.4358x over previous
//
#include <hip/hip_runtime.h>
#include <stdint.h>

#define B_    8
#define CCH   64
#define HW_   4096
#define C512  512
#define XSTR  3176   // shorts per xl kgrp (396*8=3168 + 8 pad -> 6352 B, bank-staggered)
#define WSTR  528    // shorts per wl (tap,lkg) sub-block (64*8=512 + 16 pad -> 1056 B)

typedef __attribute__((ext_vector_type(8))) short short8v;
typedef __attribute__((ext_vector_type(4))) float f32x4;
typedef __attribute__((ext_vector_type(4))) unsigned short ushort4v;

__device__ __constant__ int PERM[8][8] = {
  {0,1,2,3,4,5,6,7},
  {3,0,1,2,5,6,7,4},
  {2,3,0,1,6,7,4,5},
  {1,2,3,0,7,4,5,6},
  {4,5,6,7,0,1,2,3},
  {5,6,7,4,3,0,1,2},
  {6,7,4,5,2,3,0,1},
  {7,4,5,6,1,2,3,0},
};

__device__ inline float bf2f(unsigned int u){
  union { unsigned int i; float f; } v; v.i = u << 16; return v.f;
}
__device__ inline unsigned short f2bf(float f){
  union { float f; unsigned int i; } v; v.f = f;
  return (unsigned short)((v.i + 0x7FFFu + ((v.i >> 16) & 1u)) >> 16);
}
// round-half-up pairwise pack (cheap; |err| <= 1ulp, fine vs 0.109 threshold)
__device__ inline unsigned int scale2(unsigned int packed, float a0, float a1, float f){
  float v0 = bf2f(packed & 0xffffu) * a0 * f;
  float v1 = bf2f(packed >> 16)     * a1 * f;
  unsigned int i0 = __float_as_uint(v0), i1 = __float_as_uint(v1);
  return ((i0 + 0x8000u) >> 16) | ((i1 + 0x8000u) & 0xffff0000u);
}
__device__ inline float sigmoidf_(float x){ return 1.f / (1.f + __expf(-x)); }

__device__ __forceinline__ void gload_lds16(const unsigned short* g, unsigned short* l){
  __builtin_amdgcn_global_load_lds(
      (const __attribute__((address_space(1))) unsigned int*)(g),
      (__attribute__((address_space(3))) unsigned int*)(l), 16, 0, 0);
}

// ---------------- BN + ReLU + transpose body + fused channel AND spatial stats -----------
template<int BF>
__device__ __forceinline__ void bnrelu_body(
    const float* __restrict__ xf, const unsigned short* __restrict__ xb,
    const float* __restrict__ gamma, const float* __restrict__ beta,
    const float* __restrict__ mean,  const float* __restrict__ var,
    unsigned short* __restrict__ yT,
    float* __restrict__ csum, unsigned int* __restrict__ cmax,
    float* __restrict__ f2, int bid){
  __shared__ float lds[64 * 66];
  int b  = bid >> 9;
  int r  = bid & 511;
  int ct = r >> 6, pt = r & 63;
  int c0 = ct * 64, p0 = pt * 64;
  int t  = threadIdx.x;
  int cc = t >> 2, q = t & 3;
  int c512 = c0 + cc;
  int ch = c512 >> 3;
  float inv = gamma[ch] * rsqrtf(var[ch] + 2e-5f);
  float sh  = beta[ch] - mean[ch] * inv;
  float s_ = 0.f, m_ = 0.f;
#pragma unroll
  for (int i = 0; i < 4; ++i){
    float r0, r1, r2, r3;
    if (BF){
      const unsigned short* src = xb + ((size_t)(b * C512 + c512)) * HW_ + p0;
      ushort4v u = *(const ushort4v*)(src + i * 16 + q * 4);
      r0 = bf2f(u[0]); r1 = bf2f(u[1]); r2 = bf2f(u[2]); r3 = bf2f(u[3]);
    } else {
      const float* src = xf + ((size_t)(b * C512 + c512)) * HW_ + p0;
      float4 v = *(const float4*)(src + i * 16 + q * 4);
      r0 = v.x; r1 = v.y; r2 = v.z; r3 = v.w;
    }
    float a0 = fmaxf(r0 * inv + sh, 0.f);
    float a1 = fmaxf(r1 * inv + sh, 0.f);
    float a2 = fmaxf(r2 * inv + sh, 0.f);
    float a3 = fmaxf(r3 * inv + sh, 0.f);
    int pp = i * 16 + q * 4;
    lds[(pp + 0) * 66 + cc] = a0;
    lds[(pp + 1) * 66 + cc] = a1;
    lds[(pp + 2) * 66 + cc] = a2;
    lds[(pp + 3) * 66 + cc] = a3;
    s_ += (a0 + a1) + (a2 + a3);
    m_ = fmaxf(m_, fmaxf(fmaxf(a0, a1), fmaxf(a2, a3)));
  }
  s_ += __shfl_down(s_, 2); s_ += __shfl_down(s_, 1);
  m_ = fmaxf(m_, __shfl_down(m_, 2)); m_ = fmaxf(m_, __shfl_down(m_, 1));
  if (q == 0){
    atomicAdd(&csum[b * C512 + c512], s_);
    atomicMax(&cmax[b * C512 + c512], __float_as_uint(m_));
  }
  __syncthreads();
  // transposed bf16 store
  int cc4 = (t & 15) * 4, g0 = t >> 4;
  unsigned short* dst = yT + ((size_t)(b * HW_ + p0)) * C512 + c0 + cc4;
#pragma unroll
  for (int i = 0; i < 4; ++i){
    int pp = i * 16 + g0;
    float2 v0 = *(const float2*)&lds[pp * 66 + cc4];
    float2 v1 = *(const float2*)&lds[pp * 66 + cc4 + 2];
    ushort4v o;
    o[0] = f2bf(v0.x); o[1] = f2bf(v0.y); o[2] = f2bf(v1.x); o[3] = f2bf(v1.y);
    *(ushort4v*)(dst + (size_t)pp * C512) = o;
  }
  // fused spatial stats: reduce this block's 8 ci per (s, px), merge via atomics.
#pragma unroll
  for (int k = 0; k < 2; ++k){
    int task = t + k * 256;
    int px = task >> 3, s = task & 7;
    const float* row = &lds[px * 66 + s];
    float sm = row[0], mx = row[0];
#pragma unroll
    for (int j = 1; j < 8; ++j){ float v = row[j * 8]; sm += v; mx = fmaxf(mx, v); }
    atomicAdd(&f2[((size_t)(b * 2 + 0) * 8 + s) * 4096 + p0 + px], sm);
    atomicMax((unsigned int*)&f2[((size_t)(b * 2 + 1) * 8 + s) * 4096 + p0 + px],
              __float_as_uint(mx));
  }
}

template<int BF>
__global__ void k_bnrelu_tr(const float* __restrict__ xf, const unsigned short* __restrict__ xb,
                            const float* __restrict__ gamma, const float* __restrict__ beta,
                            const float* __restrict__ mean,  const float* __restrict__ var,
                            unsigned short* __restrict__ yT,
                            float* __restrict__ csum, unsigned int* __restrict__ cmax,
                            float* __restrict__ f2){
  bnrelu_body<BF>(xf, xb, gamma, beta, mean, var, yT, csum, cmax, f2, blockIdx.x);
}

// ---------------- conv-weight transform body -> wt[g][kc16][tap9][kl4][co64][8] bf16 ------
__device__ __forceinline__ void cw_body(const float* __restrict__ w,
                                        unsigned short* __restrict__ wt, int e){
  int j  = e & 7;
  int co = (e >> 3) & 63;
  int kl = (e >> 9) & 3;
  int r  = e >> 11;          // ((g*16 + kc)*9 + tap)
  int tap = r % 9; int r2 = r / 9;
  int kc = r2 & 15; int g = r2 >> 4;
  int c512 = kc * 32 + kl * 8 + j;
  int ci = c512 >> 3, s = c512 & 7;
  int ty = tap / 3, tx = tap % 3;
  int a = g >> 2, bb = g & 3;
  int sy, sx;
  if      (bb == 0){ sy = ty;     sx = tx;     }
  else if (bb == 1){ sy = tx;     sx = 2 - ty; }
  else if (bb == 2){ sy = 2 - ty; sx = 2 - tx; }
  else             { sy = 2 - tx; sx = ty;     }
  if (a) sx = 2 - sx;
  int ps = PERM[g][s];
  wt[e] = f2bf(w[((size_t)(co * 64 + ci) * 8 + ps) * 9 + sy * 3 + sx]);
}

// K7 (layer 0): weight transform + zero stat buffers (64 KB) + zero f2 (2 MB)
__global__ void k_cw(const float* __restrict__ w, unsigned short* __restrict__ wt,
                     unsigned int* __restrict__ zbuf, float* __restrict__ f2){
  int e = blockIdx.x * 256 + threadIdx.x;
  if (e < 16384) zbuf[e] = 0u;
  if (e < 524288) f2[e] = 0.f;
  if (e >= 8 * 16 * 9 * 4 * 64 * 8) return;
  cw_body(w, wt, e);
}

// Merged (layer 1): blocks 0..9215 = cw(L1); blocks 9216..13311 = bnrelu<bf16>(L1).
__global__ void k_cwbn(const float* __restrict__ w, unsigned short* __restrict__ wt,
                       const unsigned short* __restrict__ h1b,
                       const float* __restrict__ gamma, const float* __restrict__ beta,
                       const float* __restrict__ mean,  const float* __restrict__ var,
                       unsigned short* __restrict__ yT,
                       float* __restrict__ csum, unsigned int* __restrict__ cmax,
                       float* __restrict__ f2){
  int bid = blockIdx.x;
  if (bid < 9216){
    int e = bid * 256 + threadIdx.x;
    if (e < 8 * 16 * 9 * 4 * 64 * 8) cw_body(w, wt, e);
    return;
  }
  bnrelu_body<1>(nullptr, h1b, gamma, beta, mean, var, yT, csum, cmax, f2, bid - 9216);
}

// ---------------- K_att: blocks 0..63 = channel-MLP -> ac ; blocks 64..319 = sconv -> sp --
__global__ void k_att(const float* __restrict__ f2, const float* __restrict__ saw,
                      float* __restrict__ sp,
                      const float* __restrict__ csum, const unsigned int* __restrict__ cmax,
                      const float* __restrict__ w1, const float* __restrict__ w2,
                      float* __restrict__ ac){
  __shared__ __align__(16) float shm[16260];   // 65,040 B, aliased by both halves
  int bid = blockIdx.x;
  int t = threadIdx.x;
  if (bid < 64){
    float* vA = shm;            // 512
    float* vM = shm + 512;      // 512
    float* wred = shm + 1024;   // 16
    float* rr = shm + 1040;     // 2
    int b = bid >> 3, g = bid & 7;
    for (int j = t; j < 512; j += 256){
      int c = j >> 3, h = j & 7;
      int srcj = (c << 3) + PERM[g][h];
      vA[j] = csum[b * 512 + srcj] * (1.f / 4096.f);
      vM[j] = __uint_as_float(cmax[b * 512 + srcj]);
    }
    __syncthreads();
    float pa0 = 0, pa1 = 0, pm0 = 0, pm1 = 0;
    for (int j = t; j < 512; j += 256){
      float wa = w1[j], wb = w1[512 + j];
      pa0 += vA[j] * wa; pa1 += vA[j] * wb;
      pm0 += vM[j] * wa; pm1 += vM[j] * wb;
    }
#pragma unroll
    for (int off = 32; off >= 1; off >>= 1){
      pa0 += __shfl_down(pa0, off); pa1 += __shfl_down(pa1, off);
      pm0 += __shfl_down(pm0, off); pm1 += __shfl_down(pm1, off);
    }
    int wv = t >> 6, ln = t & 63;
    if (ln == 0){ wred[wv*4+0] = pa0; wred[wv*4+1] = pa1; wred[wv*4+2] = pm0; wred[wv*4+3] = pm1; }
    __syncthreads();
    if (t == 0){
      float hA0 = wred[0] + wred[4] + wred[8]  + wred[12];
      float hA1 = wred[1] + wred[5] + wred[9]  + wred[13];
      float hM0 = wred[2] + wred[6] + wred[10] + wred[14];
      float hM1 = wred[3] + wred[7] + wred[11] + wred[15];
      rr[0] = fmaxf(hA0, 0.f) + fmaxf(hM0, 0.f);
      rr[1] = fmaxf(hA1, 0.f) + fmaxf(hM1, 0.f);
    }
    __syncthreads();
    float r0 = rr[0], r1 = rr[1];
    for (int j = t; j < 512; j += 256){
      float z = r0 * w2[j * 2] + r1 * w2[j * 2 + 1];
      ac[(size_t)(b * 8 + g) * 512 + j] = sigmoidf_(z);
    }
    return;
  }
  float* slab = shm;            // 8960
  float* wspl = shm + 8960;     // 6272
  float* part = shm + 15232;    // 1024
  int sb = bid - 64;
  int b = sb >> 5, strip = sb & 31;
  int R0 = strip * 2;
  for (int i = t; i < 6272; i += 256){
    int g = i & 7; int r = i >> 3;
    int kx = r % 7; int r2 = r / 7;
    int ky = r2 % 7; int tc = r2 / 7;
    int m = tc >> 3, s = tc & 7;
    int a = g >> 2, bb = g & 3;
    int sy, sx;
    if      (bb == 0){ sy = ky;     sx = kx;     }
    else if (bb == 1){ sy = kx;     sx = 6 - ky; }
    else if (bb == 2){ sy = 6 - ky; sx = 6 - kx; }
    else             { sy = 6 - kx; sx = ky;     }
    if (a) sx = 6 - sx;
    int ps = PERM[g][s];
    float wv_ = saw[((m * 8 + ps) * 7 + sy) * 7 + sx];
    wspl[i] = (m == 0) ? wv_ * 0.015625f : wv_;
  }
  for (int i = t; i < 8960; i += 256){
    int tc = i / 560; int rem = i - tc * 560;
    int rr = rem / 70; int cc = rem - rr * 70;
    int gr = R0 + rr - 3, gc = cc - 3;
    float v = 0.f;
    if ((unsigned)gr < 64u && (unsigned)gc < 64u)
      v = f2[((size_t)(b * 16 + tc)) * 4096 + gr * 64 + gc];
    slab[i] = v;
  }
  __syncthreads();
  int tcH = t >> 7, p = t & 127;
  int r = p >> 6, x = p & 63;
  float acc[8] = {0,0,0,0,0,0,0,0};
  for (int tc = tcH * 8; tc < tcH * 8 + 8; ++tc){
    const float* sl = &slab[tc * 560 + r * 70 + x];
    for (int ky = 0; ky < 7; ++ky){
#pragma unroll
      for (int kx = 0; kx < 7; ++kx){
        float v = sl[ky * 70 + kx];
        const float* w8 = &wspl[((tc * 7 + ky) * 7 + kx) * 8];
#pragma unroll
        for (int g = 0; g < 8; ++g) acc[g] += v * w8[g];
      }
    }
  }
  if (tcH == 1){
#pragma unroll
    for (int g = 0; g < 8; ++g) part[p * 8 + g] = acc[g];
  }
  __syncthreads();
  if (tcH == 0){
    int px = strip * 128 + p;
#pragma unroll
    for (int g = 0; g < 8; ++g){
      float z = acc[g] + part[p * 8 + g];
      sp[((size_t)(b * 8 + g)) * 4096 + px] = sigmoidf_(z);
    }
  }
}

// ---------------- K8: main group conv (implicit GEMM, 16x16x32 bf16 MFMA) -----------------
// R18-proven best: R15 schedule + bank-stagger padding (152.4 us).
// RES==0: write h1 as bf16 AND re-zero f2 for layer 2.
template<int RES>
__global__ __launch_bounds__(256, 2)
void k_conv(const unsigned short* __restrict__ yT, const unsigned short* __restrict__ wt,
            const float* __restrict__ ac, const float* __restrict__ sp,
            const float* __restrict__ resid, float* __restrict__ outF,
            unsigned short* __restrict__ outB, float* __restrict__ f2z){
  __shared__ __align__(16) unsigned short xl[4 * XSTR];    // 25,408 B
  __shared__ __align__(16) unsigned short wl[36 * WSTR];   // 38,016 B
  __shared__ float acs[512];                               //  2,048 B  (total 65,472)
  int bid0 = blockIdx.x;
  int t = threadIdx.x;
  if (RES == 0){
    // re-zero f2 for layer-2's bnrelu atomics (att(L0) has already consumed f2)
    *(float2*)&f2z[(size_t)(bid0 * 256 + t) * 2] = make_float2(0.f, 0.f);
  }
  int bid = (bid0 & 7) * 128 + (bid0 >> 3);  // XCD swizzle (1024 = 8*128, bijective)
  int b = bid >> 7, g = (bid >> 4) & 7, tile = bid & 15;
  int r0 = tile * 4;
  int wv = t >> 6, ln = t & 63;
  int lrow = ln & 15, lkg = ln >> 4;
  int cg = t & 3;

  const unsigned short* ybase = yT + ((size_t)b * HW_) * C512;
  const unsigned short* wbase = wt + ((size_t)g) * 16 * 9 * 2048;
  const float* spb = sp + ((size_t)(b * 8 + g)) * 4096;

  // ---- hoisted staging geometry (constant across kc) ----
  unsigned int goff[7];
  float        fsc[7];
  int          xwb[7];
  uint4        xr[7];
#pragma unroll
  for (int it = 0; it < 7; ++it){
    int task = t + it * 256;
    bool act = (it < 6) || (t < 48);
    int hp = task >> 2;
    int hr = hp / 66, hc = hp - hr * 66;
    int gh = r0 + hr - 1, gw = hc - 1;
    bool inb = act && ((unsigned)gh < 64u) && ((unsigned)gw < 64u);
    goff[it] = inb ? (unsigned)((gh * 64 + gw) * C512 + cg * 8) : 0u;
    fsc[it]  = inb ? spb[gh * 64 + gw] : 0.f;
    xwb[it]  = cg * XSTR + hp * 8;
  }

  // ---- prologue: DMA W(0), prefetch X(0), fill acs ----
#pragma unroll
  for (int it = 0; it < 9; ++it){
    int task = t + it * 256;
    int sub = task >> 6, row = task & 63;
    gload_lds16(wbase + (size_t)task * 8, &wl[sub * WSTR + row * 8]);
  }
#pragma unroll
  for (int it = 0; it < 7; ++it)
    xr[it] = *(const uint4*)(ybase + goff[it]);
  for (int j = t; j < 512; j += 256) acs[j] = ac[(size_t)(b * 8 + g) * 512 + j];

  f32x4 acc[4][4];
#pragma unroll
  for (int mi = 0; mi < 4; ++mi)
#pragma unroll
    for (int ni = 0; ni < 4; ++ni)
      acc[mi][ni] = (f32x4){0.f, 0.f, 0.f, 0.f};
  __syncthreads();   // drains DMA(0) + X(0) loads; acs visible

  // ---- scale + write X(0) ----
  {
    float4 a8lo = *(const float4*)&acs[cg * 8];
    float4 a8hi = *(const float4*)&acs[cg * 8 + 4];
#pragma unroll
    for (int it = 0; it < 7; ++it){
      if (it < 6 || t < 48){
        float f = fsc[it];
        uint4 u = xr[it]; uint4 o;
        o.x = scale2(u.x, a8lo.x, a8lo.y, f);
        o.y = scale2(u.y, a8lo.z, a8lo.w, f);
        o.z = scale2(u.z, a8hi.x, a8hi.y, f);
        o.w = scale2(u.w, a8hi.z, a8hi.w, f);
        *(uint4*)&xl[xwb[it]] = o;
      }
    }
  }

  for (int kc = 0; kc < 16; ++kc){
    __syncthreads();   // xl(kc)/wl(kc) ready
    // ---- prefetch X(kc+1) (pinned before MFMA; drains under it) ----
    if (kc < 15){
#pragma unroll
      for (int it = 0; it < 7; ++it)
        xr[it] = *(const uint4*)(ybase + goff[it] + (kc + 1) * 32);
    }
    __builtin_amdgcn_sched_barrier(0);
    // ---- MFMA over LDS(kc) ----
    __builtin_amdgcn_s_setprio(1);
#pragma unroll
    for (int tap = 0; tap < 9; ++tap){
      const int ty = tap / 3, tx = tap % 3;
      short8v a[4], bv[4];
#pragma unroll
      for (int mi = 0; mi < 4; ++mi)
        a[mi] = *(const short8v*)&wl[(tap * 4 + lkg) * WSTR + (mi * 16 + lrow) * 8];
#pragma unroll
      for (int ni = 0; ni < 4; ++ni){
        int hp = (wv + ty) * 66 + ni * 16 + lrow + tx;
        bv[ni] = *(const short8v*)&xl[lkg * XSTR + hp * 8];
      }
#pragma unroll
      for (int mi = 0; mi < 4; ++mi)
#pragma unroll
        for (int ni = 0; ni < 4; ++ni)
          acc[mi][ni] = __builtin_amdgcn_mfma_f32_16x16x32_bf16(a[mi], bv[ni], acc[mi][ni], 0, 0, 0);
    }
    __builtin_amdgcn_s_setprio(0);
    __syncthreads();   // all reads of LDS(kc) done; X(kc+1) drained
    if (kc < 15){
      // ---- DMA W(kc+1) (in flight during X scale; drained at next top barrier) ----
      const unsigned short* wkc = wbase + (size_t)(kc + 1) * 9 * 2048;
#pragma unroll
      for (int it = 0; it < 9; ++it){
        int task = t + it * 256;
        int sub = task >> 6, row = task & 63;
        gload_lds16(wkc + (size_t)task * 8, &wl[sub * WSTR + row * 8]);
      }
      // ---- scale + write X(kc+1) ----
      int cb = (kc + 1) * 32;
      float4 a8lo = *(const float4*)&acs[cb + cg * 8];
      float4 a8hi = *(const float4*)&acs[cb + cg * 8 + 4];
#pragma unroll
      for (int it = 0; it < 7; ++it){
        if (it < 6 || t < 48){
          float f = fsc[it];
          uint4 u = xr[it]; uint4 o;
          o.x = scale2(u.x, a8lo.x, a8lo.y, f);
          o.y = scale2(u.y, a8lo.z, a8lo.w, f);
          o.z = scale2(u.z, a8hi.x, a8hi.y, f);
          o.w = scale2(u.w, a8hi.z, a8hi.w, f);
          *(uint4*)&xl[xwb[it]] = o;
        }
      }
    }
  }

  // ---- epilogue: C[co, pixel] -> [b][co][g][h][w]; RES? f32+resid : bf16 (h1) ----
#pragma unroll
  for (int mi = 0; mi < 4; ++mi){
#pragma unroll
    for (int ni = 0; ni < 4; ++ni){
      int n = wv * 64 + ni * 16 + lrow;
      int rr_ = n >> 6, ww = n & 63;
      int gh = r0 + rr_;
#pragma unroll
      for (int q = 0; q < 4; ++q){
        int co = mi * 16 + (ln >> 4) * 4 + q;
        size_t oidx = ((size_t)(b * 64 + co) * 8 + g) * 4096 + gh * 64 + ww;
        if (RES){
          outF[oidx] = acc[mi][ni][q] + resid[oidx];
        } else {
          outB[oidx] = f2bf(acc[mi][ni][q]);
        }
      }
    }
  }
}

// =========================================================================================
extern "C" void kernel_launch(void* const* d_in, const int* in_sizes, int n_in,
                              void* d_out, int out_size, void* d_ws, size_t ws_size,
                              hipStream_t stream){
  const size_t off_yT  = 0;                          // 33,554,432
  const size_t off_wt  = off_yT  + 33554432;         //  4,718,592
  const size_t off_f2  = off_wt  + 4718592;          //  2,097,152
  const size_t off_cs0 = off_f2  + 2097152;          //     16,384
  const size_t off_cm0 = off_cs0 + 16384;            //     16,384
  const size_t off_cs1 = off_cm0 + 16384;            //     16,384
  const size_t off_cm1 = off_cs1 + 16384;            //     16,384
  const size_t off_sp  = off_cm1 + 16384;            //  1,048,576
  const size_t off_ac  = off_sp  + 1048576;          //  1,048,576
  const size_t total   = off_ac  + 1048576;          // 42,532,864
  if (ws_size < total) return;

  char* ws = (char*)d_ws;
  unsigned short* yT  = (unsigned short*)(ws + off_yT);
  unsigned short* wtb = (unsigned short*)(ws + off_wt);
  float* f2    = (float*)(ws + off_f2);
  float* csum0 = (float*)(ws + off_cs0);
  unsigned int* cmax0 = (unsigned int*)(ws + off_cm0);
  float* csum1 = (float*)(ws + off_cs1);
  unsigned int* cmax1 = (unsigned int*)(ws + off_cm1);
  float* spb   = (float*)(ws + off_sp);
  float* acb   = (float*)(ws + off_ac);

  const float* x = (const float*)d_in[0];
  // h1 stored as bf16 in the UPPER half of d_out (33,554,432 B each half).
  unsigned short* h1b = (unsigned short*)((char*)d_out + 33554432);

  // ---- layer 0 ----
  // k_cw zeroes csum0..cmax1 (64 KB, contiguous after f2) + f2 (2 MB)
  k_cw<<<9216, 256, 0, stream>>>((const float*)d_in[5], wtb, (unsigned int*)csum0, f2);
  k_bnrelu_tr<0><<<4096, 256, 0, stream>>>(x, nullptr,
      (const float*)d_in[1], (const float*)d_in[2], (const float*)d_in[3], (const float*)d_in[4],
      yT, csum0, cmax0, f2);
  k_att<<<320, 256, 0, stream>>>(f2, (const float*)d_in[8], spb, csum0, cmax0,
      (const float*)d_in[6], (const float*)d_in[7], acb);
  k_conv<0><<<1024, 256, 0, stream>>>(yT, wtb, acb, spb, nullptr, nullptr, h1b, f2);

  // ---- layer 1 (cw(L1) merged with bnrelu(L1); f2 re-zeroed by k_conv<0>) ----
  k_cwbn<<<13312, 256, 0, stream>>>((const float*)d_in[13], wtb, h1b,
      (const float*)d_in[9], (const float*)d_in[10], (const float*)d_in[11], (const float*)d_in[12],
      yT, csum1, cmax1, f2);
  k_att<<<320, 256, 0, stream>>>(f2, (const float*)d_in[16], spb, csum1, cmax1,
      (const float*)d_in[14], (const float*)d_in[15], acb);
  k_conv<1><<<1024, 256, 0, stream>>>(yT, wtb, acb, spb, x, (float*)d_out, nullptr, nullptr);
}